// Round 9
// baseline (1189.782 us; speedup 1.0000x reference)
//
#include <hip/hip_runtime.h>
#include <hip/hip_bf16.h>

#define F_IN 128
#define NPB 256      // dst nodes per bucket
#define NPB_SH 8
#define MAXB 512     // static LDS bucket-array size (requires N <= 131072)
#define CHUNK 4096   // edges per histogram/scatter block (391 blocks)

typedef __attribute__((ext_vector_type(8))) short short8;   // 8 bf16 (4 VGPRs)
typedef __attribute__((ext_vector_type(4))) float f32x4;    // MFMA accumulator

// ---------------------------------------------------------------- bf16 helpers (storage; math in fp32)

__device__ __forceinline__ float bf2f(unsigned short u) {
    return __uint_as_float(((unsigned int)u) << 16);
}
__device__ __forceinline__ unsigned short f2bf(float f) {
    unsigned int x = __float_as_uint(f);
    x += 0x7FFFu + ((x >> 16) & 1u);   // round-to-nearest-even
    return (unsigned short)(x >> 16);
}
// 8 bf16 (uint4) -> w*val atomically added into acc[k*256 + d], k = 0..7 (+k0)
__device__ __forceinline__ void ds_acc8(float w, uint4 r, float* accd, int k0) {
    atomicAdd(accd + (k0 + 0) * 256, w * __uint_as_float(r.x << 16));
    atomicAdd(accd + (k0 + 1) * 256, w * __uint_as_float(r.x & 0xFFFF0000u));
    atomicAdd(accd + (k0 + 2) * 256, w * __uint_as_float(r.y << 16));
    atomicAdd(accd + (k0 + 3) * 256, w * __uint_as_float(r.y & 0xFFFF0000u));
    atomicAdd(accd + (k0 + 4) * 256, w * __uint_as_float(r.z << 16));
    atomicAdd(accd + (k0 + 5) * 256, w * __uint_as_float(r.z & 0xFFFF0000u));
    atomicAdd(accd + (k0 + 6) * 256, w * __uint_as_float(r.w << 16));
    atomicAdd(accd + (k0 + 7) * 256, w * __uint_as_float(r.w & 0xFFFF0000u));
}

// ---------------------------------------------------------------- weight prep: W0 -> W0t bf16 [64][128]; W1 -> W1t bf16 [32][64]
__global__ __launch_bounds__(256) void prep_w_kernel(
    const float* __restrict__ W0, const float* __restrict__ W1,
    unsigned short* __restrict__ W0t, unsigned short* __restrict__ W1t) {
    int t = blockIdx.x * 256 + threadIdx.x;
    int stride = gridDim.x * 256;
    for (int o = t; o < 64 * 128; o += stride) {
        int n = o >> 7, k = o & 127;
        W0t[o] = f2bf(W0[k * 64 + n]);
    }
    for (int o = t; o < 32 * 64; o += stride) {
        int n = o >> 6, k = o & 63;
        W1t[o] = f2bf(W1[k * 32 + n]);
    }
}

// ---------------------------------------------------------------- pass 1a: per-chunk histogram + reservation
__global__ __launch_bounds__(256) void hist_kernel(
    const int* __restrict__ dst, int* __restrict__ gcursor,
    int* __restrict__ blockres, int E, int nbucket) {
    __shared__ int hist[MAXB];
    const int tid = threadIdx.x;
    const int e0 = blockIdx.x * CHUNK;
    const int e1 = min(e0 + CHUNK, E);
    for (int b = tid; b < nbucket; b += 256) hist[b] = 0;
    __syncthreads();
    for (int e = e0 + tid; e < e1; e += 256)
        atomicAdd(&hist[dst[e] >> NPB_SH], 1);
    __syncthreads();
    int* res = blockres + (size_t)blockIdx.x * nbucket;
    for (int b = tid; b < nbucket; b += 256)
        res[b] = atomicAdd(&gcursor[b], hist[b]);
}

// exclusive scan of bucket counts (nb <= 512), bbase[nb] = total
__global__ __launch_bounds__(512) void bucket_scan_kernel(const int* __restrict__ gcursor,
                                                          int* __restrict__ bbase, int nb) {
    __shared__ int tmp[512];
    int i = threadIdx.x;
    int v = (i < nb) ? gcursor[i] : 0;
    tmp[i] = v;
    __syncthreads();
    for (int o = 1; o < 512; o <<= 1) {
        int t = (i >= o) ? tmp[i - o] : 0;
        __syncthreads();
        tmp[i] += t;
        __syncthreads();
    }
    if (i < nb) bbase[i] = tmp[i] - v;
    if (i == nb - 1) bbase[nb] = tmp[i];
}

// ---------------------------------------------------------------- pass 1b: place edges into bucket segments
// tmp entry: {src | (dst&255)<<17, bits(w)}  (src < 2^17). NOT sorted within
// bucket (random dst order is good: avoids same-address LDS-atomic runs).
__global__ __launch_bounds__(256) void scatter_bucket_kernel(
    const int* __restrict__ src, const int* __restrict__ dst,
    const float* __restrict__ ew, const int* __restrict__ bbase,
    const int* __restrict__ blockres, int2* __restrict__ tmp,
    int E, int nbucket) {
    __shared__ int base[MAXB];
    __shared__ int cur[MAXB];
    const int tid = threadIdx.x;
    const int e0 = blockIdx.x * CHUNK;
    const int e1 = min(e0 + CHUNK, E);
    const int* res = blockres + (size_t)blockIdx.x * nbucket;
    for (int b = tid; b < nbucket; b += 256) {
        base[b] = bbase[b] + res[b];
        cur[b] = 0;
    }
    __syncthreads();
    for (int e = e0 + tid; e < e1; e += 256) {
        int d = dst[e];
        int b = d >> NPB_SH;
        int r = atomicAdd(&cur[b], 1);
        tmp[base[b] + r] =
            make_int2(src[e] | ((d & (NPB - 1)) << 17), __float_as_int(ew[e]));
    }
}

// ---------------------------------------------------------------- per-bucket dinv (replaces CSR build)
__global__ __launch_bounds__(256) void dinv_bucket_kernel(
    const int2* __restrict__ tmp, const int* __restrict__ bbase,
    float* __restrict__ dinv, int N) {
    __shared__ float dw[256];
    const int t = threadIdx.x;
    dw[t] = 0.f;
    __syncthreads();
    const int bb = bbase[blockIdx.x], be = bbase[blockIdx.x + 1];
    for (int p = bb + t; p < be; p += 256) {
        int2 e = tmp[p];
        atomicAdd(&dw[e.x >> 17], __int_as_float(e.y));
    }
    __syncthreads();
    int n = (blockIdx.x << NPB_SH) + t;
    if (n < N) dinv[n] = rsqrtf(fmaxf(1.f + dw[t], 1e-12f));
}

// ---------------------------------------------------------------- gemm1 (MFMA): M = bf16(dinv * (X f32 @ W0)), K=128, NOUT=64
__global__ __launch_bounds__(256) void gemm1_mfma_kernel(
    const float* __restrict__ X, const unsigned short* __restrict__ W0t,
    const float* __restrict__ dinv, unsigned short* __restrict__ M, int N) {
    __shared__ unsigned short Bs[64][136];
    const int tid = threadIdx.x;
    for (int i = tid; i < 64 * 32; i += 256) {
        int n = i >> 5, k4 = i & 31;
        ushort4 v = ((const ushort4*)W0t)[i];
        *(ushort4*)&Bs[n][k4 * 4] = v;
    }
    __syncthreads();
    const int wave = tid >> 6, lane = tid & 63;
    const int m = lane & 15, q = lane >> 4;
    const int rowA = blockIdx.x * 64 + wave * 16 + m;
    const bool rok = rowA < N;
    const float* xrow = X + (size_t)rowA * 128;
    f32x4 acc[4] = {};
#pragma unroll
    for (int ks = 0; ks < 4; ++ks) {
        int k0 = ks * 32 + q * 8;
        float4 u0 = make_float4(0.f, 0.f, 0.f, 0.f);
        float4 u1 = make_float4(0.f, 0.f, 0.f, 0.f);
        if (rok) {
            u0 = *(const float4*)(xrow + k0);
            u1 = *(const float4*)(xrow + k0 + 4);
        }
        short8 a;
        a[0] = (short)f2bf(u0.x); a[1] = (short)f2bf(u0.y);
        a[2] = (short)f2bf(u0.z); a[3] = (short)f2bf(u0.w);
        a[4] = (short)f2bf(u1.x); a[5] = (short)f2bf(u1.y);
        a[6] = (short)f2bf(u1.z); a[7] = (short)f2bf(u1.w);
#pragma unroll
        for (int ct = 0; ct < 4; ++ct) {
            short8 b = *(const short8*)&Bs[ct * 16 + m][k0];
            acc[ct] = __builtin_amdgcn_mfma_f32_16x16x32_bf16(a, b, acc[ct], 0, 0, 0);
        }
    }
#pragma unroll
    for (int r = 0; r < 4; ++r) {
        int crow = blockIdx.x * 64 + wave * 16 + q * 4 + r;
        if (crow < N) {
            float d = dinv[crow];
#pragma unroll
            for (int ct = 0; ct < 4; ++ct)
                M[(size_t)crow * 64 + ct * 16 + m] = f2bf(acc[ct][r] * d);
        }
    }
}

// ---------------------------------------------------------------- gemm2 (MFMA): m1p = bf16(dinv * (H1 bf16 @ W1)), K=64, NOUT=32
__global__ __launch_bounds__(256) void gemm2_mfma_kernel(
    const unsigned short* __restrict__ H1, const unsigned short* __restrict__ W1t,
    const float* __restrict__ dinv, unsigned short* __restrict__ M, int N) {
    __shared__ unsigned short Bs[32][72];
    const int tid = threadIdx.x;
    for (int i = tid; i < 32 * 16; i += 256) {
        int n = i >> 4, k4 = i & 15;
        ushort4 v = ((const ushort4*)W1t)[i];
        *(ushort4*)&Bs[n][k4 * 4] = v;
    }
    __syncthreads();
    const int wave = tid >> 6, lane = tid & 63;
    const int m = lane & 15, q = lane >> 4;
    const int rowA = blockIdx.x * 64 + wave * 16 + m;
    const bool rok = rowA < N;
    const short8 az = {0, 0, 0, 0, 0, 0, 0, 0};
    f32x4 acc[2] = {};
#pragma unroll
    for (int ks = 0; ks < 2; ++ks) {
        int k0 = ks * 32 + q * 8;
        short8 a = rok ? *(const short8*)(H1 + (size_t)rowA * 64 + k0) : az;
#pragma unroll
        for (int ct = 0; ct < 2; ++ct) {
            short8 b = *(const short8*)&Bs[ct * 16 + m][k0];
            acc[ct] = __builtin_amdgcn_mfma_f32_16x16x32_bf16(a, b, acc[ct], 0, 0, 0);
        }
    }
#pragma unroll
    for (int r = 0; r < 4; ++r) {
        int crow = blockIdx.x * 64 + wave * 16 + q * 4 + r;
        if (crow < N) {
            float d = dinv[crow];
#pragma unroll
            for (int ct = 0; ct < 2; ++ct)
                M[(size_t)crow * 32 + ct * 16 + m] = f2bf(acc[ct][r] * d);
        }
    }
}

// ---------------------------------------------------------------- pull1 edge-centric: block = (bucket, feature-half)
// acc[k][d] (transposed) accumulates sum_e w*m0'[src][f0+k]; finalize adds
// self-loop + bias, relu, writes H1 bf16.
__global__ __launch_bounds__(256) void pull1_lds_kernel(
    const int2* __restrict__ tmp, const int* __restrict__ bbase,
    const unsigned short* __restrict__ M, const float* __restrict__ dinv,
    const float* __restrict__ bias, unsigned short* __restrict__ H1, int N) {
    __shared__ float acc[32 * 256];   // 32 KB, [feat][node]: atomic bank = dst%32
    const int t = threadIdx.x;
    const int bucket = blockIdx.x >> 1;
    const int f0 = (blockIdx.x & 1) * 32;
#pragma unroll
    for (int i = 0; i < 32; ++i) acc[i * 256 + t] = 0.f;
    __syncthreads();
    const int bb = bbase[bucket], be = bbase[bucket + 1];
    for (int p = bb + t; p < be; p += 256) {
        int2 e = tmp[p];
        int s = e.x & 0x1FFFF;
        float w = __int_as_float(e.y);
        const unsigned short* row = M + (size_t)s * 64 + f0;
        uint4 r0 = *(const uint4*)(row);
        uint4 r1 = *(const uint4*)(row + 8);
        uint4 r2 = *(const uint4*)(row + 16);
        uint4 r3 = *(const uint4*)(row + 24);
        float* accd = acc + (e.x >> 17);
        ds_acc8(w, r0, accd, 0);
        ds_acc8(w, r1, accd, 8);
        ds_acc8(w, r2, accd, 16);
        ds_acc8(w, r3, accd, 24);
    }
    __syncthreads();
    const int n = (bucket << NPB_SH) + t;
    if (n < N) {
        const unsigned short* srow = M + (size_t)n * 64 + f0;
        float d = dinv[n];
        unsigned short o[32];
#pragma unroll
        for (int k = 0; k < 32; ++k) {
            float self = bf2f(srow[k]);
            float v = fmaf(d, acc[k * 256 + t] + self, bias[f0 + k]);
            o[k] = f2bf(fmaxf(v, 0.f));
        }
        unsigned short* hrow = H1 + (size_t)n * 64 + f0;
#pragma unroll
        for (int i = 0; i < 4; ++i) {
            uint4 pk;
            pk.x = (unsigned int)o[i*8+0] | ((unsigned int)o[i*8+1] << 16);
            pk.y = (unsigned int)o[i*8+2] | ((unsigned int)o[i*8+3] << 16);
            pk.z = (unsigned int)o[i*8+4] | ((unsigned int)o[i*8+5] << 16);
            pk.w = (unsigned int)o[i*8+6] | ((unsigned int)o[i*8+7] << 16);
            *(uint4*)(hrow + i * 8) = pk;
        }
    }
}

// ---------------------------------------------------------------- pull2 + pool edge-centric: block = (bucket, 16-feat half)
// acc -> h2 in LDS -> run-length pool using sorted ngi (staged in LDS).
__global__ __launch_bounds__(256) void pull2_pool_lds_kernel(
    const int2* __restrict__ tmp, const int* __restrict__ bbase,
    const unsigned short* __restrict__ M, const float* __restrict__ dinv,
    const float* __restrict__ bias, const int* __restrict__ ngi,
    float* __restrict__ g, int N) {
    __shared__ float acc[16 * 256];   // 16 KB
    __shared__ int ngL[256];
    const int t = threadIdx.x;
    const int bucket = blockIdx.x >> 1;
    const int f0 = (blockIdx.x & 1) * 16;
    const int n0 = bucket << NPB_SH;
#pragma unroll
    for (int i = 0; i < 16; ++i) acc[i * 256 + t] = 0.f;
    ngL[t] = (n0 + t < N) ? ngi[n0 + t] : -1;
    __syncthreads();
    const int bb = bbase[bucket], be = bbase[bucket + 1];
    for (int p = bb + t; p < be; p += 256) {
        int2 e = tmp[p];
        int s = e.x & 0x1FFFF;
        float w = __int_as_float(e.y);
        const unsigned short* row = M + (size_t)s * 32 + f0;
        uint4 r0 = *(const uint4*)(row);
        uint4 r1 = *(const uint4*)(row + 8);
        float* accd = acc + (e.x >> 17);
        ds_acc8(w, r0, accd, 0);
        ds_acc8(w, r1, accd, 8);
    }
    __syncthreads();
    const int n = n0 + t;
    if (n < N) {                        // finalize: overwrite acc with h2
        const unsigned short* srow = M + (size_t)n * 32 + f0;
        float d = dinv[n];
#pragma unroll
        for (int k = 0; k < 16; ++k) {
            float self = bf2f(srow[k]);
            float v = fmaf(d, acc[k * 256 + t] + self, bias[f0 + k]);
            acc[k * 256 + t] = fmaxf(v, 0.f);
        }
    }
    __syncthreads();
    // pool: thread = (feat 0..15) x (chunk 0..15 of 16 nodes); rotated index
    // (jj+f)&15 keeps banks distinct across the 16 feats of a half-wave.
    {
        const int f = t & 15, c = t >> 4;
        float partial = 0.f;
        int cur = -1;
        for (int jj = 0; jj < 16; ++jj) {
            int j = c * 16 + ((jj + f) & 15);
            int gi = ngL[j];
            if (gi < 0) continue;
            float v = acc[f * 256 + j];
            if (gi != cur) {
                if (cur >= 0) atomicAdd(&g[cur * 32 + f0 + f], partial);
                cur = gi;
                partial = v;
            } else {
                partial += v;
            }
        }
        if (cur >= 0) atomicAdd(&g[cur * 32 + f0 + f], partial);
    }
}

// ---------------------------------------------------------------- MLP head
__global__ __launch_bounds__(128) void mlp_kernel(
    const float* __restrict__ g, const float* __restrict__ Wm1,
    const float* __restrict__ bm1, const float* __restrict__ Wm2,
    const float* __restrict__ bm2, float* __restrict__ out) {
    __shared__ float sg[32];
    __shared__ float st[128];
    int b = blockIdx.x, t = threadIdx.x;
    if (t < 32) sg[t] = g[b * 32 + t];
    __syncthreads();
    float acc = bm1[t];
#pragma unroll
    for (int k = 0; k < 32; ++k) acc = fmaf(sg[k], Wm1[k * 128 + t], acc);
    st[t] = fmaxf(acc, 0.f);
    __syncthreads();
    if (t < 2) {
        float o = bm2[t];
#pragma unroll
        for (int k = 0; k < 128; ++k) o = fmaf(st[k], Wm2[k * 2 + t], o);
        out[b * 2 + t] = o;
    }
}

// ---------------------------------------------------------------- launch

extern "C" void kernel_launch(void* const* d_in, const int* in_sizes, int n_in,
                              void* d_out, int out_size, void* d_ws, size_t ws_size,
                              hipStream_t stream) {
    const float* x   = (const float*)d_in[0];
    const int*   ei  = (const int*)d_in[1];
    const float* ew  = (const float*)d_in[2];
    const int*   ngi = (const int*)d_in[3];
    const float* W0  = (const float*)d_in[4];
    const float* b0  = (const float*)d_in[5];
    const float* W1  = (const float*)d_in[6];
    const float* b1  = (const float*)d_in[7];
    const float* Wm1 = (const float*)d_in[8];
    const float* bm1 = (const float*)d_in[9];
    const float* Wm2 = (const float*)d_in[10];
    const float* bm2 = (const float*)d_in[11];
    float* out = (float*)d_out;

    const int N = in_sizes[0] / F_IN;       // 100000 (< 2^17, packing requirement)
    const int E = in_sizes[1] / 2;          // 1600000
    const int G = out_size / 2;             // 1000
    const int* srcp = ei;
    const int* dstp = ei + E;
    const int NBUCKET = (N + NPB - 1) >> NPB_SH;       // 391
    const int NBLK = (E + CHUNK - 1) / CHUNK;          // 391

    // workspace layout (256B-aligned chunks)
    char* wsb = (char*)d_ws;
    size_t off = 0;
    auto alloc = [&](size_t bytes) {
        char* p = wsb + off;
        off += (bytes + 255) & ~(size_t)255;
        return p;
    };
    float* dinv     = (float*)alloc((size_t)N * 4);
    int*   gcursor  = (int*)  alloc((size_t)NBUCKET * 4);
    int*   bbase    = (int*)  alloc((size_t)(NBUCKET + 1) * 4);
    int*   blockres = (int*)  alloc((size_t)NBLK * NBUCKET * 4);
    int2*  tmp      = (int2*) alloc((size_t)E * 8);    // bucketed edges (live through both pulls)
    unsigned short* W0t = (unsigned short*)alloc(64 * 128 * 2);
    unsigned short* W1t = (unsigned short*)alloc(32 * 64 * 2);
    unsigned short* M   = (unsigned short*)alloc((size_t)N * 64 * 2);  // m0' bf16; m1' aliases low half later
    unsigned short* H1  = (unsigned short*)alloc((size_t)N * 64 * 2);  // h1 bf16
    float* Gbuf     = (float*)alloc((size_t)G * 32 * 4);
    unsigned short* m1p = M;            // N*32 bf16 (m0' dead after pull1)

    // 1. weight prep + bucketed edge build + dinv
    hipMemsetAsync(gcursor, 0, (size_t)NBUCKET * 4, stream);
    prep_w_kernel<<<8, 256, 0, stream>>>(W0, W1, W0t, W1t);
    hist_kernel<<<NBLK, 256, 0, stream>>>(dstp, gcursor, blockres, E, NBUCKET);
    bucket_scan_kernel<<<1, 512, 0, stream>>>(gcursor, bbase, NBUCKET);
    scatter_bucket_kernel<<<NBLK, 256, 0, stream>>>(srcp, dstp, ew, bbase, blockres, tmp, E, NBUCKET);
    dinv_bucket_kernel<<<NBUCKET, 256, 0, stream>>>(tmp, bbase, dinv, N);

    // 2. layer 1: m0' = bf16(dinv*(x@W0)) via MFMA; edge-centric pull -> H1 bf16
    gemm1_mfma_kernel<<<(N + 63) / 64, 256, 0, stream>>>(x, W0t, dinv, M, N);
    pull1_lds_kernel<<<NBUCKET * 2, 256, 0, stream>>>(tmp, bbase, M, dinv, b0, H1, N);

    // 3. layer 2: m1' = bf16(dinv*(h1@W1)) via MFMA; edge-centric pull + fused pool
    gemm2_mfma_kernel<<<(N + 63) / 64, 256, 0, stream>>>(H1, W1t, dinv, m1p, N);
    hipMemsetAsync(Gbuf, 0, (size_t)G * 32 * 4, stream);
    pull2_pool_lds_kernel<<<NBUCKET * 2, 256, 0, stream>>>(tmp, bbase, m1p, dinv, b1, ngi, Gbuf, N);

    // 4. MLP head
    mlp_kernel<<<G, 128, 0, stream>>>(Gbuf, Wm1, bm1, Wm2, bm2, out);
}

// Round 10
// 256.660 us; speedup vs baseline: 4.6356x; 4.6356x over previous
//
#include <hip/hip_runtime.h>
#include <hip/hip_bf16.h>

#define F_IN 128
#define NPB 256      // dst nodes per bucket
#define NPB_SH 8
#define MAXB 512     // static LDS bucket-array size (requires N <= 131072)
#define CHUNK 4096   // edges per bucketing block (391 blocks -> full machine)
#define CAP 5120     // padded per-bucket segment capacity (mean 4096, sigma 64)

typedef __attribute__((ext_vector_type(8))) short short8;   // 8 bf16 (4 VGPRs)
typedef __attribute__((ext_vector_type(4))) float f32x4;    // MFMA accumulator

// ---------------------------------------------------------------- bf16 helpers (storage; math in fp32)

__device__ __forceinline__ float bf2f(unsigned short u) {
    return __uint_as_float(((unsigned int)u) << 16);
}
__device__ __forceinline__ unsigned short f2bf(float f) {
    unsigned int x = __float_as_uint(f);
    x += 0x7FFFu + ((x >> 16) & 1u);   // round-to-nearest-even
    return (unsigned short)(x >> 16);
}
// unpack 8 bf16 (uint4) and fma into a[0..8)
__device__ __forceinline__ void bf8_fma(float w, uint4 r, float* a) {
    a[0] = fmaf(w, __uint_as_float(r.x << 16), a[0]);
    a[1] = fmaf(w, __uint_as_float(r.x & 0xFFFF0000u), a[1]);
    a[2] = fmaf(w, __uint_as_float(r.y << 16), a[2]);
    a[3] = fmaf(w, __uint_as_float(r.y & 0xFFFF0000u), a[3]);
    a[4] = fmaf(w, __uint_as_float(r.z << 16), a[4]);
    a[5] = fmaf(w, __uint_as_float(r.z & 0xFFFF0000u), a[5]);
    a[6] = fmaf(w, __uint_as_float(r.w << 16), a[6]);
    a[7] = fmaf(w, __uint_as_float(r.w & 0xFFFF0000u), a[7]);
}

// ---------------------------------------------------------------- weight prep: W0 -> W0t bf16 [64][128]; W1 -> W1t bf16 [32][64]
__global__ __launch_bounds__(256) void prep_w_kernel(
    const float* __restrict__ W0, const float* __restrict__ W1,
    unsigned short* __restrict__ W0t, unsigned short* __restrict__ W1t) {
    int t = blockIdx.x * 256 + threadIdx.x;
    int stride = gridDim.x * 256;
    for (int o = t; o < 64 * 128; o += stride) {
        int n = o >> 7, k = o & 127;
        W0t[o] = f2bf(W0[k * 64 + n]);
    }
    for (int o = t; o < 32 * 64; o += stride) {
        int n = o >> 6, k = o & 63;
        W1t[o] = f2bf(W1[k * 32 + n]);
    }
}

// ---------------------------------------------------------------- fused bucketing: hist + reserve + place into padded segments
// tmp[b*CAP + ...] entry: {src | (dst&255)<<17, bits(w)}  (src < 2^17)
// gcursor[b] ends as the bucket's edge count.
__global__ __launch_bounds__(256) void bucket_fused_kernel(
    const int* __restrict__ src, const int* __restrict__ dst,
    const float* __restrict__ ew, int* __restrict__ gcursor,
    int2* __restrict__ tmp, int E, int nbucket) {
    __shared__ int hist[MAXB];
    __shared__ int gbase[MAXB];
    const int tid = threadIdx.x;
    const int e0 = blockIdx.x * CHUNK;
    const int e1 = min(e0 + CHUNK, E);
    for (int b = tid; b < nbucket; b += 256) hist[b] = 0;
    __syncthreads();
    for (int e = e0 + tid; e < e1; e += 256)
        atomicAdd(&hist[dst[e] >> NPB_SH], 1);
    __syncthreads();
    for (int b = tid; b < nbucket; b += 256) {
        int h = hist[b];
        gbase[b] = (h > 0) ? atomicAdd(&gcursor[b], h) : 0;
        hist[b] = 0;   // reuse as local cursor
    }
    __syncthreads();
    for (int e = e0 + tid; e < e1; e += 256) {
        int d = dst[e];
        int b = d >> NPB_SH;
        int r = atomicAdd(&hist[b], 1);
        tmp[(size_t)b * CAP + gbase[b] + r] =
            make_int2(src[e] | ((d & (NPB - 1)) << 17), __float_as_int(ew[e]));
    }
}

// ---------------------------------------------------------------- per-bucket CSR (padded) + rstart/rend + dinv
__global__ __launch_bounds__(256) void csr_kernel(
    const int2* __restrict__ tmp, const int* __restrict__ gcursor,
    int2* __restrict__ es, int* __restrict__ rstart, int* __restrict__ rend,
    float* __restrict__ dinv, int N) {
    __shared__ int cnt[256];
    __shared__ float dw[256];
    __shared__ int off[256];
    __shared__ int cur[256];
    const int t = threadIdx.x;
    const int n0 = blockIdx.x << NPB_SH;
    const size_t seg = (size_t)blockIdx.x * CAP;
    cnt[t] = 0;
    dw[t] = 0.f;
    __syncthreads();
    const int count = gcursor[blockIdx.x];
    for (int p = t; p < count; p += 256) {
        int2 e = tmp[seg + p];
        int d = e.x >> 17;
        atomicAdd(&cnt[d], 1);
        atomicAdd(&dw[d], __int_as_float(e.y));
    }
    __syncthreads();
    int v = cnt[t];
    off[t] = v;
    __syncthreads();
    for (int o = 1; o < 256; o <<= 1) {
        int x = (t >= o) ? off[t - o] : 0;
        __syncthreads();
        off[t] += x;
        __syncthreads();
    }
    int excl = off[t] - v;
    cur[t] = excl;
    int n = n0 + t;
    if (n < N) {
        rstart[n] = (int)seg + excl;
        rend[n] = (int)seg + excl + v;
        dinv[n] = rsqrtf(fmaxf(1.f + dw[t], 1e-12f));
    }
    __syncthreads();
    for (int p = t; p < count; p += 256) {
        int2 e = tmp[seg + p];
        int d = e.x >> 17;
        int r = atomicAdd(&cur[d], 1);
        es[seg + r] = make_int2(e.x & 0x1FFFF, e.y);
    }
}

// ---------------------------------------------------------------- gemm1 (MFMA): M = bf16(dinv * (X f32 @ W0)), K=128, NOUT=64
__global__ __launch_bounds__(256) void gemm1_mfma_kernel(
    const float* __restrict__ X, const unsigned short* __restrict__ W0t,
    const float* __restrict__ dinv, unsigned short* __restrict__ M, int N) {
    __shared__ unsigned short Bs[64][136];
    const int tid = threadIdx.x;
    for (int i = tid; i < 64 * 32; i += 256) {
        int n = i >> 5, k4 = i & 31;
        ushort4 v = ((const ushort4*)W0t)[i];
        *(ushort4*)&Bs[n][k4 * 4] = v;
    }
    __syncthreads();
    const int wave = tid >> 6, lane = tid & 63;
    const int m = lane & 15, q = lane >> 4;
    const int rowA = blockIdx.x * 64 + wave * 16 + m;
    const bool rok = rowA < N;
    const float* xrow = X + (size_t)rowA * 128;
    f32x4 acc[4] = {};
#pragma unroll
    for (int ks = 0; ks < 4; ++ks) {
        int k0 = ks * 32 + q * 8;
        float4 u0 = make_float4(0.f, 0.f, 0.f, 0.f);
        float4 u1 = make_float4(0.f, 0.f, 0.f, 0.f);
        if (rok) {
            u0 = *(const float4*)(xrow + k0);
            u1 = *(const float4*)(xrow + k0 + 4);
        }
        short8 a;
        a[0] = (short)f2bf(u0.x); a[1] = (short)f2bf(u0.y);
        a[2] = (short)f2bf(u0.z); a[3] = (short)f2bf(u0.w);
        a[4] = (short)f2bf(u1.x); a[5] = (short)f2bf(u1.y);
        a[6] = (short)f2bf(u1.z); a[7] = (short)f2bf(u1.w);
#pragma unroll
        for (int ct = 0; ct < 4; ++ct) {
            short8 b = *(const short8*)&Bs[ct * 16 + m][k0];
            acc[ct] = __builtin_amdgcn_mfma_f32_16x16x32_bf16(a, b, acc[ct], 0, 0, 0);
        }
    }
#pragma unroll
    for (int r = 0; r < 4; ++r) {
        int crow = blockIdx.x * 64 + wave * 16 + q * 4 + r;
        if (crow < N) {
            float d = dinv[crow];
#pragma unroll
            for (int ct = 0; ct < 4; ++ct)
                M[(size_t)crow * 64 + ct * 16 + m] = f2bf(acc[ct][r] * d);
        }
    }
}

// ---------------------------------------------------------------- gemm2 (MFMA): m1p = bf16(dinv * (H1 bf16 @ W1)), K=64, NOUT=32
__global__ __launch_bounds__(256) void gemm2_mfma_kernel(
    const unsigned short* __restrict__ H1, const unsigned short* __restrict__ W1t,
    const float* __restrict__ dinv, unsigned short* __restrict__ M, int N) {
    __shared__ unsigned short Bs[32][72];
    const int tid = threadIdx.x;
    for (int i = tid; i < 32 * 16; i += 256) {
        int n = i >> 4, k4 = i & 15;
        ushort4 v = ((const ushort4*)W1t)[i];
        *(ushort4*)&Bs[n][k4 * 4] = v;
    }
    __syncthreads();
    const int wave = tid >> 6, lane = tid & 63;
    const int m = lane & 15, q = lane >> 4;
    const int rowA = blockIdx.x * 64 + wave * 16 + m;
    const bool rok = rowA < N;
    const short8 az = {0, 0, 0, 0, 0, 0, 0, 0};
    f32x4 acc[2] = {};
#pragma unroll
    for (int ks = 0; ks < 2; ++ks) {
        int k0 = ks * 32 + q * 8;
        short8 a = rok ? *(const short8*)(H1 + (size_t)rowA * 64 + k0) : az;
#pragma unroll
        for (int ct = 0; ct < 2; ++ct) {
            short8 b = *(const short8*)&Bs[ct * 16 + m][k0];
            acc[ct] = __builtin_amdgcn_mfma_f32_16x16x32_bf16(a, b, acc[ct], 0, 0, 0);
        }
    }
#pragma unroll
    for (int r = 0; r < 4; ++r) {
        int crow = blockIdx.x * 64 + wave * 16 + q * 4 + r;
        if (crow < N) {
            float d = dinv[crow];
#pragma unroll
            for (int ct = 0; ct < 2; ++ct)
                M[(size_t)crow * 32 + ct * 16 + m] = f2bf(acc[ct][r] * d);
        }
    }
}

// ---------------------------------------------------------------- pull1: 2 nodes/wave x 4 chains x 8 lanes(16B), unroll-2
// H1[node] = bf16( relu( dinv*(m'[node] + sum w*m'[src]) + b0 ) )
__global__ __launch_bounds__(256) void pull1_kernel(
    const int* __restrict__ rstart, const int* __restrict__ rend,
    const int2* __restrict__ es, const unsigned short* __restrict__ M,
    const float* __restrict__ dinv, const float* __restrict__ bias,
    unsigned short* __restrict__ H1, int N) {
    const int lane = threadIdx.x & 63;
    const int wave = threadIdx.x >> 6;
    const int nd = lane >> 5;              // node within wave (0..1)
    const int node = blockIdx.x * 8 + wave * 2 + nd;
    if (node >= N) return;                 // shuffles stay within 32-lane half
    const int c = lane & 7;                // feature octet (8 bf16 = 16 B)
    const int q = (lane >> 3) & 3;         // chain 0..3
    float acc[8] = {0.f, 0.f, 0.f, 0.f, 0.f, 0.f, 0.f, 0.f};
    if (q == 0) {                           // self-loop counted once
        uint4 r = *(const uint4*)(M + (size_t)node * 64 + c * 8);
        bf8_fma(1.f, r, acc);
    }
    const int b = rstart[node], e = rend[node];
    int p = b + q;
    const int e4 = e - 4;
    for (; p < e4; p += 8) {                // 2 edges in flight per chain
        int2 ed0 = es[p];
        int2 ed1 = es[p + 4];
        uint4 r0 = *(const uint4*)(M + (size_t)ed0.x * 64 + c * 8);
        uint4 r1 = *(const uint4*)(M + (size_t)ed1.x * 64 + c * 8);
        bf8_fma(__int_as_float(ed0.y), r0, acc);
        bf8_fma(__int_as_float(ed1.y), r1, acc);
    }
    if (p < e) {
        int2 ed = es[p];
        uint4 r = *(const uint4*)(M + (size_t)ed.x * 64 + c * 8);
        bf8_fma(__int_as_float(ed.y), r, acc);
    }
#pragma unroll
    for (int off = 8; off <= 16; off <<= 1)   // reduce across 4 chains
#pragma unroll
        for (int k = 0; k < 8; ++k) acc[k] += __shfl_xor(acc[k], off);
    if (q == 0) {
        float d = dinv[node];
        const float* bp = bias + c * 8;
        float4 b0v = *(const float4*)(bp);
        float4 b1v = *(const float4*)(bp + 4);
        unsigned short o[8];
        o[0] = f2bf(fmaxf(fmaf(d, acc[0], b0v.x), 0.f));
        o[1] = f2bf(fmaxf(fmaf(d, acc[1], b0v.y), 0.f));
        o[2] = f2bf(fmaxf(fmaf(d, acc[2], b0v.z), 0.f));
        o[3] = f2bf(fmaxf(fmaf(d, acc[3], b0v.w), 0.f));
        o[4] = f2bf(fmaxf(fmaf(d, acc[4], b1v.x), 0.f));
        o[5] = f2bf(fmaxf(fmaf(d, acc[5], b1v.y), 0.f));
        o[6] = f2bf(fmaxf(fmaf(d, acc[6], b1v.z), 0.f));
        o[7] = f2bf(fmaxf(fmaf(d, acc[7], b1v.w), 0.f));
        uint4 pk;
        pk.x = (unsigned int)o[0] | ((unsigned int)o[1] << 16);
        pk.y = (unsigned int)o[2] | ((unsigned int)o[3] << 16);
        pk.z = (unsigned int)o[4] | ((unsigned int)o[5] << 16);
        pk.w = (unsigned int)o[6] | ((unsigned int)o[7] << 16);
        *(uint4*)(H1 + (size_t)node * 64 + c * 8) = pk;
    }
}

// ---------------------------------------------------------------- pull2 + fused sum-pool: 4 nodes/wave x 4 chains x 4 lanes(16B), unroll-2
__global__ __launch_bounds__(256) void pull2_pool_kernel(
    const int* __restrict__ rstart, const int* __restrict__ rend,
    const int2* __restrict__ es, const unsigned short* __restrict__ M,
    const float* __restrict__ dinv, const float* __restrict__ bias,
    const int* __restrict__ ngi, float* __restrict__ g, int N) {
    __shared__ float4 sh[16][8];
    __shared__ int sgx[16];
    const int t = threadIdx.x;
    const int lane = t & 63;
    const int nl = t >> 4;                 // node local 0..15 (= wave*4 + nd)
    const int node = blockIdx.x * 16 + nl;
    const int c = lane & 3;                // feature octet (8 bf16 of 32)
    const int q = (lane >> 2) & 3;         // chain 0..3
    const bool valid = node < N;
    float acc[8] = {0.f, 0.f, 0.f, 0.f, 0.f, 0.f, 0.f, 0.f};
    if (valid) {
        if (q == 0) {
            uint4 r = *(const uint4*)(M + (size_t)node * 32 + c * 8);
            bf8_fma(1.f, r, acc);
        }
        const int b = rstart[node], e = rend[node];
        int p = b + q;
        const int e4 = e - 4;
        for (; p < e4; p += 8) {            // 2 edges in flight per chain
            int2 ed0 = es[p];
            int2 ed1 = es[p + 4];
            uint4 r0 = *(const uint4*)(M + (size_t)ed0.x * 32 + c * 8);
            uint4 r1 = *(const uint4*)(M + (size_t)ed1.x * 32 + c * 8);
            bf8_fma(__int_as_float(ed0.y), r0, acc);
            bf8_fma(__int_as_float(ed1.y), r1, acc);
        }
        if (p < e) {
            int2 ed = es[p];
            uint4 r = *(const uint4*)(M + (size_t)ed.x * 32 + c * 8);
            bf8_fma(__int_as_float(ed.y), r, acc);
        }
#pragma unroll
        for (int off = 4; off <= 8; off <<= 1)   // reduce across 4 chains
#pragma unroll
            for (int k = 0; k < 8; ++k) acc[k] += __shfl_xor(acc[k], off);
    }
    if (q == 0) {                          // 4 lanes per node hold the result
        float4 o0 = make_float4(0.f, 0.f, 0.f, 0.f);
        float4 o1 = make_float4(0.f, 0.f, 0.f, 0.f);
        if (valid) {
            float d = dinv[node];
            const float* bp = bias + c * 8;
            float4 b0v = *(const float4*)(bp);
            float4 b1v = *(const float4*)(bp + 4);
            o0.x = fmaxf(fmaf(d, acc[0], b0v.x), 0.f);
            o0.y = fmaxf(fmaf(d, acc[1], b0v.y), 0.f);
            o0.z = fmaxf(fmaf(d, acc[2], b0v.z), 0.f);
            o0.w = fmaxf(fmaf(d, acc[3], b0v.w), 0.f);
            o1.x = fmaxf(fmaf(d, acc[4], b1v.x), 0.f);
            o1.y = fmaxf(fmaf(d, acc[5], b1v.y), 0.f);
            o1.z = fmaxf(fmaf(d, acc[6], b1v.z), 0.f);
            o1.w = fmaxf(fmaf(d, acc[7], b1v.w), 0.f);
        }
        sh[nl][c * 2] = o0;
        sh[nl][c * 2 + 1] = o1;
        if (c == 0) sgx[nl] = valid ? ngi[node] : -1;
    }
    __syncthreads();
    if (t < 8) {                           // run-length combine across the block's 16 nodes
        int cc = t;
        float4 a = make_float4(0.f, 0.f, 0.f, 0.f);
        int cg = -1;
        for (int i = 0; i < 16; ++i) {
            int gi = sgx[i];
            if (gi < 0) continue;
            if (gi != cg) {
                if (cg >= 0) {
                    float* gp = g + cg * 32 + cc * 4;
                    atomicAdd(gp + 0, a.x); atomicAdd(gp + 1, a.y);
                    atomicAdd(gp + 2, a.z); atomicAdd(gp + 3, a.w);
                }
                cg = gi;
                a = sh[i][cc];
            } else {
                float4 tv = sh[i][cc];
                a.x += tv.x; a.y += tv.y; a.z += tv.z; a.w += tv.w;
            }
        }
        if (cg >= 0) {
            float* gp = g + cg * 32 + cc * 4;
            atomicAdd(gp + 0, a.x); atomicAdd(gp + 1, a.y);
            atomicAdd(gp + 2, a.z); atomicAdd(gp + 3, a.w);
        }
    }
}

// ---------------------------------------------------------------- MLP head
__global__ __launch_bounds__(128) void mlp_kernel(
    const float* __restrict__ g, const float* __restrict__ Wm1,
    const float* __restrict__ bm1, const float* __restrict__ Wm2,
    const float* __restrict__ bm2, float* __restrict__ out) {
    __shared__ float sg[32];
    __shared__ float st[128];
    int b = blockIdx.x, t = threadIdx.x;
    if (t < 32) sg[t] = g[b * 32 + t];
    __syncthreads();
    float acc = bm1[t];
#pragma unroll
    for (int k = 0; k < 32; ++k) acc = fmaf(sg[k], Wm1[k * 128 + t], acc);
    st[t] = fmaxf(acc, 0.f);
    __syncthreads();
    if (t < 2) {
        float o = bm2[t];
#pragma unroll
        for (int k = 0; k < 128; ++k) o = fmaf(st[k], Wm2[k * 2 + t], o);
        out[b * 2 + t] = o;
    }
}

// ---------------------------------------------------------------- launch

extern "C" void kernel_launch(void* const* d_in, const int* in_sizes, int n_in,
                              void* d_out, int out_size, void* d_ws, size_t ws_size,
                              hipStream_t stream) {
    const float* x   = (const float*)d_in[0];
    const int*   ei  = (const int*)d_in[1];
    const float* ew  = (const float*)d_in[2];
    const int*   ngi = (const int*)d_in[3];
    const float* W0  = (const float*)d_in[4];
    const float* b0  = (const float*)d_in[5];
    const float* W1  = (const float*)d_in[6];
    const float* b1  = (const float*)d_in[7];
    const float* Wm1 = (const float*)d_in[8];
    const float* bm1 = (const float*)d_in[9];
    const float* Wm2 = (const float*)d_in[10];
    const float* bm2 = (const float*)d_in[11];
    float* out = (float*)d_out;

    const int N = in_sizes[0] / F_IN;       // 100000 (< 2^17, packing requirement)
    const int E = in_sizes[1] / 2;          // 1600000
    const int G = out_size / 2;             // 1000
    const int* srcp = ei;
    const int* dstp = ei + E;
    const int NBUCKET = (N + NPB - 1) >> NPB_SH;       // 391
    const int NBLK = (E + CHUNK - 1) / CHUNK;          // 391

    // workspace layout (256B-aligned chunks)
    char* wsb = (char*)d_ws;
    size_t off = 0;
    auto alloc = [&](size_t bytes) {
        char* p = wsb + off;
        off += (bytes + 255) & ~(size_t)255;
        return p;
    };
    float* dinv     = (float*)alloc((size_t)N * 4);
    int*   gcursor  = (int*)  alloc((size_t)NBUCKET * 4);
    int*   rstart   = (int*)  alloc((size_t)N * 4);
    int*   rend     = (int*)  alloc((size_t)N * 4);
    int2*  tmp      = (int2*) alloc((size_t)NBUCKET * CAP * 8);   // padded bucketed edges
    int2*  es       = (int2*) alloc((size_t)NBUCKET * CAP * 8);   // padded CSR edges
    unsigned short* W0t = (unsigned short*)alloc(64 * 128 * 2);
    unsigned short* W1t = (unsigned short*)alloc(32 * 64 * 2);
    unsigned short* M   = (unsigned short*)alloc((size_t)N * 64 * 2);  // m0' bf16; m1' aliases later
    unsigned short* H1  = (unsigned short*)alloc((size_t)N * 64 * 2);  // h1 bf16
    float* Gbuf     = (float*)alloc((size_t)G * 32 * 4);
    unsigned short* m1p = M;            // N*32 bf16 (m0' dead after pull1)

    // 1. weight prep + fused bucketing + padded CSR (rstart/rend/dinv)
    hipMemsetAsync(gcursor, 0, (size_t)NBUCKET * 4, stream);
    prep_w_kernel<<<8, 256, 0, stream>>>(W0, W1, W0t, W1t);
    bucket_fused_kernel<<<NBLK, 256, 0, stream>>>(srcp, dstp, ew, gcursor, tmp, E, NBUCKET);
    csr_kernel<<<NBUCKET, 256, 0, stream>>>(tmp, gcursor, es, rstart, rend, dinv, N);

    // 2. layer 1: m0' = bf16(dinv*(x@W0)) via MFMA; pull (2 nodes/wave, 4x2 chains) -> h1 bf16
    gemm1_mfma_kernel<<<(N + 63) / 64, 256, 0, stream>>>(x, W0t, dinv, M, N);
    pull1_kernel<<<(N + 7) / 8, 256, 0, stream>>>(rstart, rend, es, M, dinv, b0, H1, N);

    // 3. layer 2: m1' = bf16(dinv*(h1@W1)) via MFMA; pull (4 nodes/wave) + fused sum-pool
    gemm2_mfma_kernel<<<(N + 63) / 64, 256, 0, stream>>>(H1, W1t, dinv, m1p, N);
    hipMemsetAsync(Gbuf, 0, (size_t)G * 32 * 4, stream);
    pull2_pool_kernel<<<(N + 15) / 16, 256, 0, stream>>>(rstart, rend, es, m1p, dinv, b1, ngi, Gbuf, N);

    // 4. MLP head
    mlp_kernel<<<G, 128, 0, stream>>>(Gbuf, Wm1, bm1, Wm2, bm2, out);
}